// Round 11
// baseline (160.907 us; speedup 1.0000x reference)
//
#include <hip/hip_runtime.h>
#include <math.h>

#define BB    32
#define TENC  1024
#define TDEC  512
#define DDIM  512
#define NST   512

typedef _Float16 f16_t;
typedef _Float16 f16x8 __attribute__((ext_vector_type(8)));
typedef _Float16 f16x4 __attribute__((ext_vector_type(4)));
typedef float    f32x4 __attribute__((ext_vector_type(4)));

#define GLOAD_LDS16(gp, lp) __builtin_amdgcn_global_load_lds( \
    (const __attribute__((address_space(1))) unsigned int*)(const void*)(gp), \
    (__attribute__((address_space(3))) unsigned int*)(lp), 16, 0, 0)

static __device__ __forceinline__ f32x4 MFMA16H(f16x8 a, f16x8 b, f32x4 c) {
    return __builtin_amdgcn_mfma_f32_16x16x32_f16(a, b, c, 0, 0, 0);
}

// ---------------------------------------------------------------------------
// Fused prep: enc->f16, dec->f16, Wk->f16, Wv->f16 transposed. One launch.
// blocks [0,8192): enc | [8192,12288): dec | [12288,12416): Wk | [12416,12480): WvT
__global__ __launch_bounds__(256)
void prep_convert(const float* __restrict__ enc, const float* __restrict__ dec,
                  const float* __restrict__ Wk, const float* __restrict__ Wv,
                  f16_t* __restrict__ Ef16, f16_t* __restrict__ dec16,
                  f16_t* __restrict__ Wk16, f16_t* __restrict__ WvT16)
{
    const int bid = blockIdx.x;
    const int t = threadIdx.x;

    if (bid < 12416) {
        const float* src; f16_t* dst; long i;
        if (bid < 8192)       { src = enc; dst = Ef16;  i = (long)bid * 256 + t; }
        else if (bid < 12288) { src = dec; dst = dec16; i = (long)(bid - 8192) * 256 + t; }
        else                  { src = Wk;  dst = Wk16;  i = (long)(bid - 12288) * 256 + t; }
        float4 a = *(const float4*)&src[i * 8];
        float4 b = *(const float4*)&src[i * 8 + 4];
        f16x8 o;
        o[0] = (f16_t)a.x; o[1] = (f16_t)a.y; o[2] = (f16_t)a.z; o[3] = (f16_t)a.w;
        o[4] = (f16_t)b.x; o[5] = (f16_t)b.y; o[6] = (f16_t)b.z; o[7] = (f16_t)b.w;
        *(f16x8*)&dst[i * 8] = o;
        return;
    }

    // Wv transpose: WvT16[v][d] = Wv[d][v].  R=DDIM rows(d), C=NST cols(v).
    __shared__ f16_t tile[64][65];
    const int r2 = bid - 12416;
    const int c0 = (r2 & 7) * 64, r0 = (r2 >> 3) * 64;
    const int rr = t >> 4;
    const int cc = (t & 15) * 4;
#pragma unroll
    for (int p = 0; p < 4; ++p) {
        int r = rr + p * 16;
        float4 v = *(const float4*)&Wv[(long)(r0 + r) * NST + c0 + cc];
        tile[r][cc + 0] = (f16_t)v.x;
        tile[r][cc + 1] = (f16_t)v.y;
        tile[r][cc + 2] = (f16_t)v.z;
        tile[r][cc + 3] = (f16_t)v.w;
    }
    __syncthreads();
    const int dr = t >> 2;
    const int tc = (t & 3) * 16;
    f16_t tmp[16];
#pragma unroll
    for (int e = 0; e < 16; ++e) tmp[e] = tile[tc + e][dr];
    *(f16x8*)&WvT16[(long)(c0 + dr) * DDIM + r0 + tc]     = *(f16x8*)&tmp[0];
    *(f16x8*)&WvT16[(long)(c0 + dr) * DDIM + r0 + tc + 8] = *(f16x8*)&tmp[8];
}

// ---------------------------------------------------------------------------
// Plain-f16 MFMA GEMM (R10-proven): C = A[M,K] @ B'[N,K]^T. EPI 2 = f16 out.
template<int EPI>
__global__ __launch_bounds__(256)
void gemm_h(const f16_t* __restrict__ A, const f16_t* __restrict__ B,
            const float* __restrict__ bias, void* __restrict__ C0,
            int M, int N, int K, long sA, long sB, long sC)
{
    __shared__ f16_t lds[2][8192];

    const int tid  = threadIdx.x;
    const int wave = tid >> 6;
    const int lane = tid & 63;

    const int gx = gridDim.x, gy = gridDim.y;
    const long nwg = (long)gx * gy * gridDim.z;
    const long fo  = ((long)blockIdx.z * gy + blockIdx.y) * gx + blockIdx.x;
    const long f2 = (fo & 7) * (nwg >> 3) + (fo >> 3);
    const int bx  = (int)(f2 % gx);
    const int by  = (int)((f2 / gx) % gy);
    const long bz = f2 / ((long)gx * gy);

    const f16_t* Ab = A + bz * sA;
    const f16_t* Bb = B + bz * sB;

    const int row0 = by * 128;
    const int col0 = bx * 128;

    const int srow  = wave * 16 + (lane >> 2);
    const int sslot = (lane & 3) ^ ((srow >> 1) & 3);
    const int wdst  = wave * 512;
    const long aOff0 = (long)(row0 + srow) * K + sslot * 8;
    const long aOff1 = (long)(row0 + 64 + srow) * K + sslot * 8;
    const long bOff0 = (long)(col0 + srow) * K + sslot * 8;
    const long bOff1 = (long)(col0 + 64 + srow) * K + sslot * 8;

    const int fr = lane & 15;
    const int q  = lane >> 4;
    const int wr = (wave >> 1) * 64;
    const int wc = (wave & 1) * 64;
    int aro[4], bro[4];
#pragma unroll
    for (int i = 0; i < 4; ++i) {
        const int r = wr + i * 16 + fr;
        aro[i] = r * 32 + ((q ^ ((r >> 1) & 3)) * 8);
    }
#pragma unroll
    for (int j = 0; j < 4; ++j) {
        const int r = wc + j * 16 + fr;
        bro[j] = r * 32 + ((q ^ ((r >> 1) & 3)) * 8);
    }

    f32x4 acc[4][4] = {};
    const int NT = K >> 5;

#define STAGE(buf, kt) do {                                   \
        GLOAD_LDS16(Ab + aOff0 + (kt), &(buf)[wdst]);         \
        GLOAD_LDS16(Ab + aOff1 + (kt), &(buf)[2048 + wdst]);  \
        GLOAD_LDS16(Bb + bOff0 + (kt), &(buf)[4096 + wdst]);  \
        GLOAD_LDS16(Bb + bOff1 + (kt), &(buf)[6144 + wdst]);  \
    } while (0)

    STAGE(lds[0], 0);

    for (int t = 0; t < NT; ++t) {
        const f16_t* cur = lds[t & 1];
        f16_t* nxt = lds[(t & 1) ^ 1];
        const bool pf = (t + 1 < NT);

        __builtin_amdgcn_sched_barrier(0);
        __builtin_amdgcn_s_barrier();
        if (pf) {
            STAGE(nxt, (t + 1) << 5);
            asm volatile("s_waitcnt vmcnt(4)" ::: "memory");
        } else {
            asm volatile("s_waitcnt vmcnt(0)" ::: "memory");
        }
        __builtin_amdgcn_s_barrier();
        __builtin_amdgcn_sched_barrier(0);

        f16x8 aH[4], bH[4];
#pragma unroll
        for (int i = 0; i < 4; ++i) aH[i] = *(const f16x8*)&cur[aro[i]];
#pragma unroll
        for (int j = 0; j < 4; ++j) bH[j] = *(const f16x8*)&cur[4096 + bro[j]];

#pragma unroll
        for (int j = 0; j < 4; ++j)
#pragma unroll
            for (int i = 0; i < 4; ++i)
                acc[i][j] = MFMA16H(aH[i], bH[j], acc[i][j]);
    }
#undef STAGE

    const int frow = q * 4;
#pragma unroll
    for (int i = 0; i < 4; ++i) {
        const int rgl = row0 + wr + i * 16 + frow;
#pragma unroll
        for (int j = 0; j < 4; ++j) {
            const int cg = col0 + wc + j * 16 + fr;
            if constexpr (EPI == 2) {
                f16_t* C = (f16_t*)C0 + bz * sC;
#pragma unroll
                for (int r = 0; r < 4; ++r)
                    C[(long)(rgl + r) * N + cg] = (f16_t)acc[i][j][r];
            } else {
                float* C = (float*)C0 + bz * sC;
                const float badd = (EPI == 3) ? bias[cg] : 0.0f;
#pragma unroll
                for (int r = 0; r < 4; ++r)
                    C[(long)(rgl + r) * N + cg] = acc[i][j][r] + badd;
            }
        }
    }
}

// ---------------------------------------------------------------------------
// Fused score+softmax: block = 32 dec rows x 1024 te (one batch z).
// 8 waves; wave w covers te [w*128, w*128+128). acc[2][8] f32x4.
// K-loop: enc-tile 1024x32 f16 (64KB, single-buffer) + DK-tile 32x32 (2KB).
// Epilogue: in-register row softmax (shfl width-16 + cross-wave LDS), writes
// attn f32 (the required output) directly. No score scratch round-trip.
__global__ __launch_bounds__(512)
void score_softmax(const f16_t* __restrict__ DK, const f16_t* __restrict__ E,
                   float* __restrict__ attn)
{
    __shared__ f16_t Bs[1024 * 32];   // 64 KB
    __shared__ f16_t As[32 * 32];     // 2 KB
    __shared__ float smx[8][32];
    __shared__ float sms[8][32];

    const int tid  = threadIdx.x;
    const int wave = tid >> 6;
    const int lane = tid & 63;

    // XCD swizzle: grid (16 row-groups, 32 batches), nwg=512 -> XCD x gets 4 batches
    const int fo = blockIdx.y * 16 + blockIdx.x;
    const int f2 = (fo & 7) * 64 + (fo >> 3);
    const int rg = f2 & 15;
    const int z  = f2 >> 4;

    const f16_t* DKb = DK + ((long)z * TDEC + rg * 32) * DDIM;
    const f16_t* Eb  = E + (long)z * TENC * DDIM;
    float* Ab = attn + (long)z * TDEC * TENC + (long)(rg * 32) * TENC;

    const int srow = lane >> 2;     // 0..15
    const int sk   = lane & 3;

    const int fr = lane & 15;
    const int q  = lane >> 4;
    const int wc = wave * 128;
    int aro[2], bro[8];
#pragma unroll
    for (int i = 0; i < 2; ++i) {
        const int r = i * 16 + fr;
        aro[i] = r * 32 + ((q ^ ((r >> 1) & 3)) * 8);
    }
#pragma unroll
    for (int j = 0; j < 8; ++j) {
        const int r = wc + j * 16 + fr;
        bro[j] = r * 32 + ((q ^ ((r >> 1) & 3)) * 8);
    }

    f32x4 acc[2][8] = {};

#define SSTAGE(ktd) do {                                                       \
        _Pragma("unroll")                                                      \
        for (int c = 0; c < 8; ++c) {                                          \
            const int rL = wave * 128 + c * 16 + srow;                         \
            const int slot = sk ^ ((rL >> 1) & 3);                             \
            GLOAD_LDS16(Eb + (long)rL * DDIM + (ktd) + slot * 8,               \
                        &Bs[(wave * 128 + c * 16) * 32]);                      \
        }                                                                      \
        if (wave == 0) {                                                       \
            _Pragma("unroll")                                                  \
            for (int c = 0; c < 2; ++c) {                                      \
                const int rA = c * 16 + srow;                                  \
                const int slot = sk ^ ((rA >> 1) & 3);                         \
                GLOAD_LDS16(DKb + (long)rA * DDIM + (ktd) + slot * 8,          \
                            &As[c * 16 * 32]);                                 \
            }                                                                  \
        }                                                                      \
    } while (0)

    SSTAGE(0);

    for (int kt = 0; kt < 16; ++kt) {
        asm volatile("s_waitcnt vmcnt(0)" ::: "memory");
        __builtin_amdgcn_s_barrier();           // tile kt in LDS (all waves)
        __builtin_amdgcn_sched_barrier(0);

        f16x8 aH[2];
        aH[0] = *(const f16x8*)&As[aro[0]];
        aH[1] = *(const f16x8*)&As[aro[1]];
#pragma unroll
        for (int j = 0; j < 8; ++j) {
            f16x8 bH = *(const f16x8*)&Bs[bro[j]];
            acc[0][j] = MFMA16H(aH[0], bH, acc[0][j]);
            acc[1][j] = MFMA16H(aH[1], bH, acc[1][j]);
        }
        asm volatile("s_waitcnt lgkmcnt(0)" ::: "memory");
        __builtin_amdgcn_sched_barrier(0);
        __builtin_amdgcn_s_barrier();           // all reads retired
        if (kt < 15) SSTAGE((kt + 1) * 32);     // overwrite LDS; drained next iter
    }
#undef SSTAGE

    // ---- in-register row softmax --------------------------------------------
    // lane holds rows r_loc = i*16 + q*4 + rr (i<2, rr<4), cols wc + j*16 + fr.
    float pm[2][4];
#pragma unroll
    for (int i = 0; i < 2; ++i)
#pragma unroll
        for (int rr = 0; rr < 4; ++rr) {
            float m = acc[i][0][rr];
#pragma unroll
            for (int j = 1; j < 8; ++j) m = fmaxf(m, acc[i][j][rr]);
            pm[i][rr] = m;
        }
#pragma unroll
    for (int o = 1; o < 16; o <<= 1)
#pragma unroll
        for (int i = 0; i < 2; ++i)
#pragma unroll
            for (int rr = 0; rr < 4; ++rr)
                pm[i][rr] = fmaxf(pm[i][rr], __shfl_xor(pm[i][rr], o, 16));
    if (fr == 0) {
#pragma unroll
        for (int i = 0; i < 2; ++i)
#pragma unroll
            for (int rr = 0; rr < 4; ++rr)
                smx[wave][i * 16 + q * 4 + rr] = pm[i][rr];
    }
    __syncthreads();
    float gm[2][4];
#pragma unroll
    for (int i = 0; i < 2; ++i)
#pragma unroll
        for (int rr = 0; rr < 4; ++rr) {
            const int row = i * 16 + q * 4 + rr;
            float m = smx[0][row];
#pragma unroll
            for (int w = 1; w < 8; ++w) m = fmaxf(m, smx[w][row]);
            gm[i][rr] = m;
        }
    float ps[2][4] = {};
#pragma unroll
    for (int i = 0; i < 2; ++i)
#pragma unroll
        for (int j = 0; j < 8; ++j)
#pragma unroll
            for (int rr = 0; rr < 4; ++rr) {
                float e = __expf(acc[i][j][rr] - gm[i][rr]);
                acc[i][j][rr] = e;
                ps[i][rr] += e;
            }
#pragma unroll
    for (int o = 1; o < 16; o <<= 1)
#pragma unroll
        for (int i = 0; i < 2; ++i)
#pragma unroll
            for (int rr = 0; rr < 4; ++rr)
                ps[i][rr] += __shfl_xor(ps[i][rr], o, 16);
    if (fr == 0) {
#pragma unroll
        for (int i = 0; i < 2; ++i)
#pragma unroll
            for (int rr = 0; rr < 4; ++rr)
                sms[wave][i * 16 + q * 4 + rr] = ps[i][rr];
    }
    __syncthreads();
#pragma unroll
    for (int i = 0; i < 2; ++i)
#pragma unroll
        for (int rr = 0; rr < 4; ++rr) {
            const int row = i * 16 + q * 4 + rr;
            float s = sms[0][row];
#pragma unroll
            for (int w = 1; w < 8; ++w) s += sms[w][row];
            const float inv = 1.0f / s;
#pragma unroll
            for (int j = 0; j < 8; ++j)
                Ab[(long)row * TENC + wc + j * 16 + fr] = acc[i][j][rr] * inv;
        }
}

// ---------------------------------------------------------------------------
// ctx GEMM: A = attn f32 (reg-staged -> f16), B = EVT f16 (gload), out f32+bias.
// R8-proven schedule (gemm_u<2,0,3>) ported to f16.
__global__ __launch_bounds__(256)
void gemm_ctx(const float* __restrict__ Af, const f16_t* __restrict__ Bh,
              const float* __restrict__ bias, float* __restrict__ C,
              int M, int N, int K, long sAf, long sB, long sC)
{
    __shared__ f16_t lds[2][8192];   // A [0,4096), B [4096,8192)

    const int tid  = threadIdx.x;
    const int wave = tid >> 6;
    const int lane = tid & 63;

    const int gx = gridDim.x, gy = gridDim.y;
    const long nwg = (long)gx * gy * gridDim.z;
    const long fo  = ((long)blockIdx.z * gy + blockIdx.y) * gx + blockIdx.x;
    const long f2 = (fo & 7) * (nwg >> 3) + (fo >> 3);
    const int bx  = (int)(f2 % gx);
    const int by  = (int)((f2 / gx) % gy);
    const long bz = f2 / ((long)gx * gy);

    const float* AfB = Af + bz * sAf;
    const f16_t* BhB = Bh + bz * sB;

    const int row0 = by * 128;
    const int col0 = bx * 128;

    const int srow  = wave * 16 + (lane >> 2);
    const int sslot = (lane & 3) ^ ((srow >> 1) & 3);
    const int wdst  = wave * 512;

    const int rrow = tid >> 3;
    const int rk4  = (tid & 7) * 4;
    const int rgr  = rk4 >> 3;
    const int rh4  = rk4 & 4;

    const int fr = lane & 15;
    const int q  = lane >> 4;
    const int wr = (wave >> 1) * 64;
    const int wc = (wave & 1) * 64;
    int aro[4], bro[4];
#pragma unroll
    for (int i = 0; i < 4; ++i) {
        const int r = wr + i * 16 + fr;
        aro[i] = r * 32 + ((q ^ ((r >> 1) & 3)) * 8);
    }
#pragma unroll
    for (int j = 0; j < 4; ++j) {
        const int r = wc + j * 16 + fr;
        bro[j] = r * 32 + ((q ^ ((r >> 1) & 3)) * 8);
    }

    f32x4 acc[4][4] = {};
    float4 rS[4];
    f16x8 aH[4], bH[4];
    const int NT = K >> 5;

    auto stageG = [&](f16_t* buf, int kt) {
#pragma unroll
        for (int c = 0; c < 2; ++c) {
            const long go = (long)(col0 + c * 64 + srow) * K + kt + sslot * 8;
            GLOAD_LDS16(BhB + go, &buf[4096 + c * 2048 + wdst]);
        }
    };
    auto loadR = [&](int kt) {
#pragma unroll
        for (int i = 0; i < 4; ++i)
            rS[i] = *(const float4*)&AfB[(long)(row0 + i * 32 + rrow) * K + kt + rk4];
    };
    auto writeR = [&](f16_t* buf) {
#pragma unroll
        for (int i = 0; i < 4; ++i) {
            const int row = i * 32 + rrow;
            const int eo  = row * 32 + ((rgr ^ ((row >> 1) & 3)) * 8) + rh4;
            f16x4 h4;
            h4[0] = (f16_t)rS[i].x; h4[1] = (f16_t)rS[i].y;
            h4[2] = (f16_t)rS[i].z; h4[3] = (f16_t)rS[i].w;
            *(f16x4*)&buf[eo] = h4;
        }
    };
    auto readF = [&](const f16_t* buf) {
#pragma unroll
        for (int i = 0; i < 4; ++i) aH[i] = *(const f16x8*)&buf[aro[i]];
#pragma unroll
        for (int j = 0; j < 4; ++j) bH[j] = *(const f16x8*)&buf[4096 + bro[j]];
    };

    loadR(0);
    stageG(lds[0], 0);
    writeR(lds[0]);
    loadR(32);
    asm volatile("s_waitcnt vmcnt(4)" ::: "memory");
    asm volatile("s_waitcnt lgkmcnt(0)" ::: "memory");
    __builtin_amdgcn_s_barrier();
    readF(lds[0]);
    asm volatile("s_waitcnt lgkmcnt(0)" ::: "memory");
    __builtin_amdgcn_s_barrier();

    for (int t = 0; t < NT; ++t) {
        f16_t* nxt = lds[(t & 1) ^ 1];
        const bool pf = (t + 1 < NT);

        if (pf) {
            writeR(nxt);
            stageG(nxt, (t + 1) << 5);
            if (t + 2 < NT) loadR((t + 2) << 5);
        }
#pragma unroll
        for (int j = 0; j < 4; ++j)
#pragma unroll
            for (int i = 0; i < 4; ++i)
                acc[i][j] = MFMA16H(aH[i], bH[j], acc[i][j]);

        if (pf && (t + 2 < NT))
            asm volatile("s_waitcnt vmcnt(4)" ::: "memory");
        else
            asm volatile("s_waitcnt vmcnt(0)" ::: "memory");
        asm volatile("s_waitcnt lgkmcnt(0)" ::: "memory");
        __builtin_amdgcn_s_barrier();
        if (pf) {
            readF(nxt);
            asm volatile("s_waitcnt lgkmcnt(0)" ::: "memory");
        }
        __builtin_amdgcn_s_barrier();
    }

    const int frow = q * 4;
#pragma unroll
    for (int i = 0; i < 4; ++i) {
        const int rgl = row0 + wr + i * 16 + frow;
#pragma unroll
        for (int j = 0; j < 4; ++j) {
            const int cg = col0 + wc + j * 16 + fr;
            float* Cp = C + bz * sC;
            const float badd = bias[cg];
#pragma unroll
            for (int r = 0; r < 4; ++r)
                Cp[(long)(rgl + r) * N + cg] = acc[i][j][r] + badd;
        }
    }
}

// ---------------------------------------------------------------------------
// Fallback pieces (fp32 path, used only if ws is too small)
__global__ __launch_bounds__(256)
void softmax_rows(float* __restrict__ S)
{
    const long row = (long)blockIdx.x * 4 + (threadIdx.x >> 6);
    const int lane = threadIdx.x & 63;
    float* p = S + row * (long)TENC;
    float4 v[4];
    float m = -INFINITY;
#pragma unroll
    for (int i = 0; i < 4; ++i) {
        v[i] = *(const float4*)&p[i * 256 + lane * 4];
        m = fmaxf(fmaxf(fmaxf(v[i].x, v[i].y), fmaxf(v[i].z, v[i].w)), m);
    }
#pragma unroll
    for (int o = 32; o; o >>= 1) m = fmaxf(m, __shfl_xor(m, o, 64));
    float s = 0.f;
#pragma unroll
    for (int i = 0; i < 4; ++i) {
        v[i].x = __expf(v[i].x - m); v[i].y = __expf(v[i].y - m);
        v[i].z = __expf(v[i].z - m); v[i].w = __expf(v[i].w - m);
        s += v[i].x + v[i].y + v[i].z + v[i].w;
    }
#pragma unroll
    for (int o = 32; o; o >>= 1) s += __shfl_xor(s, o, 64);
    const float inv = 1.0f / s;
#pragma unroll
    for (int i = 0; i < 4; ++i) {
        v[i].x *= inv; v[i].y *= inv; v[i].z *= inv; v[i].w *= inv;
        *(float4*)&p[i * 256 + lane * 4] = v[i];
    }
}

#define TILE_M 64
#define TILE_N 64
#define TILE_K 16
template<bool B_TRANS, bool ADD_BIAS>
__global__ __launch_bounds__(256)
void gemm_f32(const float* __restrict__ A, const float* __restrict__ Bm,
              const float* __restrict__ bias, float* __restrict__ C,
              int M, int N, int K, int lda, int ldb,
              long strideA, long strideB, long strideC)
{
    __shared__ float As[TILE_K][TILE_M + 4];
    __shared__ float Bs[TILE_K][TILE_N + 4];
    const int b = blockIdx.z;
    A += (long)b * strideA; Bm += (long)b * strideB; C += (long)b * strideC;
    const int tid = threadIdx.x;
    const int tx = tid & 15, ty = tid >> 4;
    const int row0 = blockIdx.y * TILE_M, col0 = blockIdx.x * TILE_N;
    const int am = tid >> 2, ak = (tid & 3) * 4;
    float acc[4][4] = {};
    for (int kt = 0; kt < K; kt += TILE_K) {
        float4 a4 = *(const float4*)&A[(long)(row0 + am) * lda + kt + ak];
        float4 b4;
        if (B_TRANS) b4 = *(const float4*)&Bm[(long)(col0 + am) * ldb + kt + ak];
        else {
            const int bk_ = tid >> 4, bn = (tid & 15) * 4;
            b4 = *(const float4*)&Bm[(long)(kt + bk_) * ldb + col0 + bn];
        }
        __syncthreads();
        As[ak + 0][am] = a4.x; As[ak + 1][am] = a4.y;
        As[ak + 2][am] = a4.z; As[ak + 3][am] = a4.w;
        if (B_TRANS) {
            Bs[ak + 0][am] = b4.x; Bs[ak + 1][am] = b4.y;
            Bs[ak + 2][am] = b4.z; Bs[ak + 3][am] = b4.w;
        } else {
            const int bk_ = tid >> 4, bn = (tid & 15) * 4;
            *(float4*)&Bs[bk_][bn] = b4;
        }
        __syncthreads();
#pragma unroll
        for (int k = 0; k < TILE_K; ++k) {
            float4 av = *(const float4*)&As[k][ty * 4];
            float4 bv4 = *(const float4*)&Bs[k][tx * 4];
            float ar[4] = {av.x, av.y, av.z, av.w};
            float br[4] = {bv4.x, bv4.y, bv4.z, bv4.w};
#pragma unroll
            for (int i = 0; i < 4; ++i)
#pragma unroll
                for (int j = 0; j < 4; ++j)
                    acc[i][j] = fmaf(ar[i], br[j], acc[i][j]);
        }
    }
    float4 bias4 = make_float4(0.f, 0.f, 0.f, 0.f);
    if (ADD_BIAS) bias4 = *(const float4*)&bias[col0 + tx * 4];
#pragma unroll
    for (int i = 0; i < 4; ++i) {
        float4 o;
        o.x = acc[i][0] + bias4.x; o.y = acc[i][1] + bias4.y;
        o.z = acc[i][2] + bias4.z; o.w = acc[i][3] + bias4.w;
        *(float4*)&C[(long)(row0 + ty * 4 + i) * N + col0 + tx * 4] = o;
    }
}

// ---------------------------------------------------------------------------
extern "C" void kernel_launch(void* const* d_in, const int* in_sizes, int n_in,
                              void* d_out, int out_size, void* d_ws, size_t ws_size,
                              hipStream_t stream)
{
    const float* enc = (const float*)d_in[0];   // [32,1024,512]
    const float* dec = (const float*)d_in[1];   // [32,512,512]
    const float* Wk  = (const float*)d_in[2];   // [512,512]
    const float* Wv  = (const float*)d_in[4];   // [512,512]
    const float* bv  = (const float*)d_in[5];   // [512]

    const long nD = (long)BB * TDEC * NST;      // 8388608

    float* ctx   = (float*)d_out;               // [32,512,512]
    float* attnF = ctx + nD;                    // [32,512,1024]

    const size_t need = 68157440;
    const dim3 blk(256);

    if (ws_size < need) {
        float* ws = (float*)d_ws;
        gemm_f32<true, false><<<dim3(DDIM / 64, (BB * TDEC) / 64, 1), blk, 0, stream>>>(
            dec, Wk, nullptr, ws, BB * TDEC, DDIM, NST, NST, NST, 0, 0, 0);
        gemm_f32<true, false><<<dim3(TENC / 64, TDEC / 64, BB), blk, 0, stream>>>(
            ws, enc, nullptr, attnF, TDEC, TENC, DDIM, DDIM, DDIM,
            (long)TDEC * DDIM, (long)TENC * DDIM, (long)TDEC * TENC);
        softmax_rows<<<(BB * TDEC) / 4, blk, 0, stream>>>(attnF);
        gemm_f32<false, false><<<dim3(DDIM / 64, TDEC / 64, BB), blk, 0, stream>>>(
            attnF, enc, nullptr, ws, TDEC, DDIM, TENC, TENC, DDIM,
            (long)TDEC * TENC, (long)TENC * DDIM, (long)TDEC * DDIM);
        gemm_f32<false, true><<<dim3(NST / 64, (BB * TDEC) / 64, 1), blk, 0, stream>>>(
            ws, Wv, bv, ctx, BB * TDEC, NST, DDIM, DDIM, NST, 0, 0, 0);
        return;
    }

    // ws: EVT 33.55MB | Ef16 33.55MB | Wk16 0.5MB | WvT16 0.5MB
    char* w = (char*)d_ws;
    f16_t* EVT   = (f16_t*)(w);
    f16_t* Ef16  = (f16_t*)(w + 33554432);
    f16_t* Wk16  = (f16_t*)(w + 67108864);
    f16_t* WvT16 = (f16_t*)(w + 67633152);

    // dec16/DK16 in the not-yet-written ctx output region (16.8MB each)
    f16_t* dec16 = (f16_t*)ctx;
    f16_t* DK16  = dec16 + nD;

    // 1) fused prep (enc/dec/Wk cvt + Wv transpose)
    prep_convert<<<12480, blk, 0, stream>>>(enc, dec, Wk, Wv,
                                            Ef16, dec16, Wk16, WvT16);

    // 2) DK = dec @ Wk^T -> f16
    gemm_h<2><<<dim3(DDIM / 128, (BB * TDEC) / 128, 1), blk, 0, stream>>>(
        dec16, Wk16, nullptr, DK16,
        BB * TDEC, DDIM, NST, 0, 0, 0);

    // 3) EVT[v,te] = sum_d Wv[d,v] enc[te,d] -> f16
    gemm_h<2><<<dim3(TENC / 128, NST / 128, BB), blk, 0, stream>>>(
        WvT16, Ef16, nullptr, EVT,
        NST, TENC, DDIM,
        0, (long)TENC * DDIM, (long)NST * TENC);

    // 4) fused score + softmax -> attn f32 (output) directly
    score_softmax<<<dim3(16, 32), dim3(512), 0, stream>>>(DK16, Ef16, attnF);

    // 5) ctx = attn @ EV + bv  (A = attn f32 reg-staged, B = EVT gload)
    gemm_ctx<<<dim3(NST / 128, TDEC / 128, BB), blk, 0, stream>>>(
        attnF, EVT, bv, ctx,
        TDEC, NST, TENC,
        (long)TDEC * TENC, (long)NST * TENC, (long)TDEC * NST);
}

// Round 14
// 157.940 us; speedup vs baseline: 1.0188x; 1.0188x over previous
//
#include <hip/hip_runtime.h>
#include <math.h>

#define BB    32
#define TENC  1024
#define TDEC  512
#define DDIM  512
#define NST   512

typedef _Float16 f16_t;
typedef _Float16 f16x8 __attribute__((ext_vector_type(8)));
typedef _Float16 f16x4 __attribute__((ext_vector_type(4)));
typedef float    f32x4 __attribute__((ext_vector_type(4)));

#define GLOAD_LDS16(gp, lp) __builtin_amdgcn_global_load_lds( \
    (const __attribute__((address_space(1))) unsigned int*)(const void*)(gp), \
    (__attribute__((address_space(3))) unsigned int*)(lp), 16, 0, 0)

static __device__ __forceinline__ f32x4 MFMA16H(f16x8 a, f16x8 b, f32x4 c) {
    return __builtin_amdgcn_mfma_f32_16x16x32_f16(a, b, c, 0, 0, 0);
}

// ---------------------------------------------------------------------------
// Fused prep: enc->f16, dec->f16, Wk->f16, Wv->f16 transposed. One launch.
__global__ __launch_bounds__(256)
void prep_convert(const float* __restrict__ enc, const float* __restrict__ dec,
                  const float* __restrict__ Wk, const float* __restrict__ Wv,
                  f16_t* __restrict__ Ef16, f16_t* __restrict__ dec16,
                  f16_t* __restrict__ Wk16, f16_t* __restrict__ WvT16)
{
    const int bid = blockIdx.x;
    const int t = threadIdx.x;

    if (bid < 12416) {
        const float* src; f16_t* dst; long i;
        if (bid < 8192)       { src = enc; dst = Ef16;  i = (long)bid * 256 + t; }
        else if (bid < 12288) { src = dec; dst = dec16; i = (long)(bid - 8192) * 256 + t; }
        else                  { src = Wk;  dst = Wk16;  i = (long)(bid - 12288) * 256 + t; }
        float4 a = *(const float4*)&src[i * 8];
        float4 b = *(const float4*)&src[i * 8 + 4];
        f16x8 o;
        o[0] = (f16_t)a.x; o[1] = (f16_t)a.y; o[2] = (f16_t)a.z; o[3] = (f16_t)a.w;
        o[4] = (f16_t)b.x; o[5] = (f16_t)b.y; o[6] = (f16_t)b.z; o[7] = (f16_t)b.w;
        *(f16x8*)&dst[i * 8] = o;
        return;
    }

    __shared__ f16_t tile[64][65];
    const int r2 = bid - 12416;
    const int c0 = (r2 & 7) * 64, r0 = (r2 >> 3) * 64;
    const int rr = t >> 4;
    const int cc = (t & 15) * 4;
#pragma unroll
    for (int p = 0; p < 4; ++p) {
        int r = rr + p * 16;
        float4 v = *(const float4*)&Wv[(long)(r0 + r) * NST + c0 + cc];
        tile[r][cc + 0] = (f16_t)v.x;
        tile[r][cc + 1] = (f16_t)v.y;
        tile[r][cc + 2] = (f16_t)v.z;
        tile[r][cc + 3] = (f16_t)v.w;
    }
    __syncthreads();
    const int dr = t >> 2;
    const int tc = (t & 3) * 16;
    f16_t tmp[16];
#pragma unroll
    for (int e = 0; e < 16; ++e) tmp[e] = tile[tc + e][dr];
    *(f16x8*)&WvT16[(long)(c0 + dr) * DDIM + r0 + tc]     = *(f16x8*)&tmp[0];
    *(f16x8*)&WvT16[(long)(c0 + dr) * DDIM + r0 + tc + 8] = *(f16x8*)&tmp[8];
}

// ---------------------------------------------------------------------------
// Plain-f16 MFMA GEMM (R10-proven): C = A[M,K] @ B'[N,K]^T. EPI 2 = f16 out.
template<int EPI>
__global__ __launch_bounds__(256)
void gemm_h(const f16_t* __restrict__ A, const f16_t* __restrict__ B,
            const float* __restrict__ bias, void* __restrict__ C0,
            int M, int N, int K, long sA, long sB, long sC)
{
    __shared__ f16_t lds[2][8192];

    const int tid  = threadIdx.x;
    const int wave = tid >> 6;
    const int lane = tid & 63;

    const int gx = gridDim.x, gy = gridDim.y;
    const long nwg = (long)gx * gy * gridDim.z;
    const long fo  = ((long)blockIdx.z * gy + blockIdx.y) * gx + blockIdx.x;
    const long f2 = (fo & 7) * (nwg >> 3) + (fo >> 3);
    const int bx  = (int)(f2 % gx);
    const int by  = (int)((f2 / gx) % gy);
    const long bz = f2 / ((long)gx * gy);

    const f16_t* Ab = A + bz * sA;
    const f16_t* Bb = B + bz * sB;

    const int row0 = by * 128;
    const int col0 = bx * 128;

    const int srow  = wave * 16 + (lane >> 2);
    const int sslot = (lane & 3) ^ ((srow >> 1) & 3);
    const int wdst  = wave * 512;
    const long aOff0 = (long)(row0 + srow) * K + sslot * 8;
    const long aOff1 = (long)(row0 + 64 + srow) * K + sslot * 8;
    const long bOff0 = (long)(col0 + srow) * K + sslot * 8;
    const long bOff1 = (long)(col0 + 64 + srow) * K + sslot * 8;

    const int fr = lane & 15;
    const int q  = lane >> 4;
    const int wr = (wave >> 1) * 64;
    const int wc = (wave & 1) * 64;
    int aro[4], bro[4];
#pragma unroll
    for (int i = 0; i < 4; ++i) {
        const int r = wr + i * 16 + fr;
        aro[i] = r * 32 + ((q ^ ((r >> 1) & 3)) * 8);
    }
#pragma unroll
    for (int j = 0; j < 4; ++j) {
        const int r = wc + j * 16 + fr;
        bro[j] = r * 32 + ((q ^ ((r >> 1) & 3)) * 8);
    }

    f32x4 acc[4][4] = {};
    const int NT = K >> 5;

#define STAGE(buf, kt) do {                                   \
        GLOAD_LDS16(Ab + aOff0 + (kt), &(buf)[wdst]);         \
        GLOAD_LDS16(Ab + aOff1 + (kt), &(buf)[2048 + wdst]);  \
        GLOAD_LDS16(Bb + bOff0 + (kt), &(buf)[4096 + wdst]);  \
        GLOAD_LDS16(Bb + bOff1 + (kt), &(buf)[6144 + wdst]);  \
    } while (0)

    STAGE(lds[0], 0);

    for (int t = 0; t < NT; ++t) {
        const f16_t* cur = lds[t & 1];
        f16_t* nxt = lds[(t & 1) ^ 1];
        const bool pf = (t + 1 < NT);

        __builtin_amdgcn_sched_barrier(0);
        __builtin_amdgcn_s_barrier();
        if (pf) {
            STAGE(nxt, (t + 1) << 5);
            asm volatile("s_waitcnt vmcnt(4)" ::: "memory");
        } else {
            asm volatile("s_waitcnt vmcnt(0)" ::: "memory");
        }
        __builtin_amdgcn_s_barrier();
        __builtin_amdgcn_sched_barrier(0);

        f16x8 aH[4], bH[4];
#pragma unroll
        for (int i = 0; i < 4; ++i) aH[i] = *(const f16x8*)&cur[aro[i]];
#pragma unroll
        for (int j = 0; j < 4; ++j) bH[j] = *(const f16x8*)&cur[4096 + bro[j]];

#pragma unroll
        for (int j = 0; j < 4; ++j)
#pragma unroll
            for (int i = 0; i < 4; ++i)
                acc[i][j] = MFMA16H(aH[i], bH[j], acc[i][j]);
    }
#undef STAGE

    const int frow = q * 4;
#pragma unroll
    for (int i = 0; i < 4; ++i) {
        const int rgl = row0 + wr + i * 16 + frow;
#pragma unroll
        for (int j = 0; j < 4; ++j) {
            const int cg = col0 + wc + j * 16 + fr;
            if constexpr (EPI == 2) {
                f16_t* C = (f16_t*)C0 + bz * sC;
#pragma unroll
                for (int r = 0; r < 4; ++r)
                    C[(long)(rgl + r) * N + cg] = (f16_t)acc[i][j][r];
            } else {
                float* C = (float*)C0 + bz * sC;
                const float badd = (EPI == 3) ? bias[cg] : 0.0f;
#pragma unroll
                for (int r = 0; r < 4; ++r)
                    C[(long)(rgl + r) * N + cg] = acc[i][j][r] + badd;
            }
        }
    }
}

// ---------------------------------------------------------------------------
// Fused score+softmax v2: block = 32 dec rows x 1024 te, in TWO te-halves.
// Per K-step stage = 512 rows x 32k (32KB) + DK 2KB -> double-buffered (70KB
// LDS, 2 blocks/CU), R10-proven barrier skeleton + counted per-wave vmcnt.
// acc0/acc1 named per half (no runtime indexing -> no scratch).
__global__ __launch_bounds__(512)
void score_softmax(const f16_t* __restrict__ DK, const f16_t* __restrict__ E,
                   float* __restrict__ attn)
{
    __shared__ f16_t Bs[2][512 * 32];   // 2 x 32 KB
    __shared__ f16_t As[2][32 * 32];    // 2 x 2 KB
    __shared__ float smx[8][32];
    __shared__ float sms[8][32];

    const int tid  = threadIdx.x;
    const int wave = tid >> 6;
    const int lane = tid & 63;

    const int fo = blockIdx.y * 16 + blockIdx.x;
    const int f2 = (fo & 7) * 64 + (fo >> 3);
    const int rg = f2 & 15;
    const int z  = f2 >> 4;

    const f16_t* DKb = DK + ((long)z * TDEC + rg * 32) * DDIM;
    const f16_t* Eb  = E + (long)z * TENC * DDIM;
    float* Ab = attn + (long)z * TDEC * TENC + (long)(rg * 32) * TENC;

    const int srow = lane >> 2;     // 0..15
    const int sk   = lane & 3;

    const int fr = lane & 15;
    const int q  = lane >> 4;
    int aro[2], bro[4];
#pragma unroll
    for (int i = 0; i < 2; ++i) {
        const int r = i * 16 + fr;
        aro[i] = r * 32 + ((q ^ ((r >> 1) & 3)) * 8);
    }
#pragma unroll
    for (int j = 0; j < 4; ++j) {
        const int r = wave * 64 + j * 16 + fr;   // local row within half-tile
        bro[j] = r * 32 + ((q ^ ((r >> 1) & 3)) * 8);
    }

    f32x4 acc0[2][4] = {};
    f32x4 acc1[2][4] = {};

    // stage (h, kt) into buffer b: enc rows h*512 + [wave*64, +64), 4 issues/wave;
    // DK rows 0..31, 2 issues (wave 0 only).
#define SSTAGE(b, h, kt) do {                                                  \
        f16_t* Bdst = Bs[b];                                                   \
        _Pragma("unroll")                                                      \
        for (int c = 0; c < 4; ++c) {                                          \
            const int rL = wave * 64 + c * 16 + srow;                          \
            const int slot = sk ^ ((rL >> 1) & 3);                             \
            GLOAD_LDS16(Eb + ((long)((h) * 512 + rL)) * DDIM + (kt) * 32 + slot * 8, \
                        &Bdst[(wave * 64 + c * 16) * 32]);                     \
        }                                                                      \
        if (wave == 0) {                                                       \
            f16_t* Adst = As[b];                                               \
            _Pragma("unroll")                                                  \
            for (int c = 0; c < 2; ++c) {                                      \
                const int rA = c * 16 + srow;                                  \
                const int slot = sk ^ ((rA >> 1) & 3);                         \
                GLOAD_LDS16(DKb + (long)rA * DDIM + (kt) * 32 + slot * 8,      \
                            &Adst[c * 16 * 32]);                               \
            }                                                                  \
        }                                                                      \
    } while (0)

#define KSTEP(ACC, it) do {                                                    \
        const bool pf = (it) + 1 < 32;                                         \
        __builtin_amdgcn_sched_barrier(0);                                     \
        __builtin_amdgcn_s_barrier();                                          \
        if (pf) {                                                              \
            SSTAGE(((it) + 1) & 1, ((it) + 1) >> 4, ((it) + 1) & 15);          \
            if (wave == 0) asm volatile("s_waitcnt vmcnt(6)" ::: "memory");    \
            else           asm volatile("s_waitcnt vmcnt(4)" ::: "memory");    \
        } else {                                                               \
            asm volatile("s_waitcnt vmcnt(0)" ::: "memory");                   \
        }                                                                      \
        __builtin_amdgcn_s_barrier();                                          \
        __builtin_amdgcn_sched_barrier(0);                                     \
        const f16_t* Acur = As[(it) & 1];                                      \
        const f16_t* Bcur = Bs[(it) & 1];                                      \
        f16x8 aH0 = *(const f16x8*)&Acur[aro[0]];                              \
        f16x8 aH1 = *(const f16x8*)&Acur[aro[1]];                              \
        _Pragma("unroll")                                                      \
        for (int j = 0; j < 4; ++j) {                                          \
            f16x8 bH = *(const f16x8*)&Bcur[bro[j]];                           \
            ACC[0][j] = MFMA16H(aH0, bH, ACC[0][j]);                           \
            ACC[1][j] = MFMA16H(aH1, bH, ACC[1][j]);                           \
        }                                                                      \
    } while (0)

    SSTAGE(0, 0, 0);
    for (int kt = 0; kt < 16; ++kt) KSTEP(acc0, kt);
    for (int kt = 0; kt < 16; ++kt) KSTEP(acc1, 16 + kt);
#undef KSTEP
#undef SSTAGE

    // ---- in-register row softmax over both halves ---------------------------
    // lane holds rows i*16 + q*4 + rr; cols h*512 + wave*64 + j*16 + fr.
    float pm[2][4];
#pragma unroll
    for (int i = 0; i < 2; ++i)
#pragma unroll
        for (int rr = 0; rr < 4; ++rr) {
            float m = acc0[i][0][rr];
#pragma unroll
            for (int j = 1; j < 4; ++j) m = fmaxf(m, acc0[i][j][rr]);
#pragma unroll
            for (int j = 0; j < 4; ++j) m = fmaxf(m, acc1[i][j][rr]);
            pm[i][rr] = m;
        }
#pragma unroll
    for (int o = 1; o < 16; o <<= 1)
#pragma unroll
        for (int i = 0; i < 2; ++i)
#pragma unroll
            for (int rr = 0; rr < 4; ++rr)
                pm[i][rr] = fmaxf(pm[i][rr], __shfl_xor(pm[i][rr], o, 16));
    if (fr == 0) {
#pragma unroll
        for (int i = 0; i < 2; ++i)
#pragma unroll
            for (int rr = 0; rr < 4; ++rr)
                smx[wave][i * 16 + q * 4 + rr] = pm[i][rr];
    }
    __syncthreads();
    float gm[2][4];
#pragma unroll
    for (int i = 0; i < 2; ++i)
#pragma unroll
        for (int rr = 0; rr < 4; ++rr) {
            const int row = i * 16 + q * 4 + rr;
            float m = smx[0][row];
#pragma unroll
            for (int w = 1; w < 8; ++w) m = fmaxf(m, smx[w][row]);
            gm[i][rr] = m;
        }
    float ps[2][4] = {};
#pragma unroll
    for (int i = 0; i < 2; ++i)
#pragma unroll
        for (int j = 0; j < 4; ++j)
#pragma unroll
            for (int rr = 0; rr < 4; ++rr) {
                float e0 = __expf(acc0[i][j][rr] - gm[i][rr]);
                float e1 = __expf(acc1[i][j][rr] - gm[i][rr]);
                acc0[i][j][rr] = e0;
                acc1[i][j][rr] = e1;
                ps[i][rr] += e0 + e1;
            }
#pragma unroll
    for (int o = 1; o < 16; o <<= 1)
#pragma unroll
        for (int i = 0; i < 2; ++i)
#pragma unroll
            for (int rr = 0; rr < 4; ++rr)
                ps[i][rr] += __shfl_xor(ps[i][rr], o, 16);
    if (fr == 0) {
#pragma unroll
        for (int i = 0; i < 2; ++i)
#pragma unroll
            for (int rr = 0; rr < 4; ++rr)
                sms[wave][i * 16 + q * 4 + rr] = ps[i][rr];
    }
    __syncthreads();
#pragma unroll
    for (int i = 0; i < 2; ++i)
#pragma unroll
        for (int rr = 0; rr < 4; ++rr) {
            const int row = i * 16 + q * 4 + rr;
            float s = sms[0][row];
#pragma unroll
            for (int w = 1; w < 8; ++w) s += sms[w][row];
            const float inv = 1.0f / s;
#pragma unroll
            for (int j = 0; j < 4; ++j) {
                Ab[(long)row * TENC + wave * 64 + j * 16 + fr]       = acc0[i][j][rr] * inv;
                Ab[(long)row * TENC + 512 + wave * 64 + j * 16 + fr] = acc1[i][j][rr] * inv;
            }
        }
}

// ---------------------------------------------------------------------------
// ctx GEMM: A = attn f32 (reg-staged -> f16), B = EVT f16 (gload), out f32+bias.
__global__ __launch_bounds__(256)
void gemm_ctx(const float* __restrict__ Af, const f16_t* __restrict__ Bh,
              const float* __restrict__ bias, float* __restrict__ C,
              int M, int N, int K, long sAf, long sB, long sC)
{
    __shared__ f16_t lds[2][8192];   // A [0,4096), B [4096,8192)

    const int tid  = threadIdx.x;
    const int wave = tid >> 6;
    const int lane = tid & 63;

    const int gx = gridDim.x, gy = gridDim.y;
    const long nwg = (long)gx * gy * gridDim.z;
    const long fo  = ((long)blockIdx.z * gy + blockIdx.y) * gx + blockIdx.x;
    const long f2 = (fo & 7) * (nwg >> 3) + (fo >> 3);
    const int bx  = (int)(f2 % gx);
    const int by  = (int)((f2 / gx) % gy);
    const long bz = f2 / ((long)gx * gy);

    const float* AfB = Af + bz * sAf;
    const f16_t* BhB = Bh + bz * sB;

    const int row0 = by * 128;
    const int col0 = bx * 128;

    const int srow  = wave * 16 + (lane >> 2);
    const int sslot = (lane & 3) ^ ((srow >> 1) & 3);
    const int wdst  = wave * 512;

    const int rrow = tid >> 3;
    const int rk4  = (tid & 7) * 4;
    const int rgr  = rk4 >> 3;
    const int rh4  = rk4 & 4;

    const int fr = lane & 15;
    const int q  = lane >> 4;
    const int wr = (wave >> 1) * 64;
    const int wc = (wave & 1) * 64;
    int aro[4], bro[4];
#pragma unroll
    for (int i = 0; i < 4; ++i) {
        const int r = wr + i * 16 + fr;
        aro[i] = r * 32 + ((q ^ ((r >> 1) & 3)) * 8);
    }
#pragma unroll
    for (int j = 0; j < 4; ++j) {
        const int r = wc + j * 16 + fr;
        bro[j] = r * 32 + ((q ^ ((r >> 1) & 3)) * 8);
    }

    f32x4 acc[4][4] = {};
    float4 rS[4];
    f16x8 aH[4], bH[4];
    const int NT = K >> 5;

    auto stageG = [&](f16_t* buf, int kt) {
#pragma unroll
        for (int c = 0; c < 2; ++c) {
            const long go = (long)(col0 + c * 64 + srow) * K + kt + sslot * 8;
            GLOAD_LDS16(BhB + go, &buf[4096 + c * 2048 + wdst]);
        }
    };
    auto loadR = [&](int kt) {
#pragma unroll
        for (int i = 0; i < 4; ++i)
            rS[i] = *(const float4*)&AfB[(long)(row0 + i * 32 + rrow) * K + kt + rk4];
    };
    auto writeR = [&](f16_t* buf) {
#pragma unroll
        for (int i = 0; i < 4; ++i) {
            const int row = i * 32 + rrow;
            const int eo  = row * 32 + ((rgr ^ ((row >> 1) & 3)) * 8) + rh4;
            f16x4 h4;
            h4[0] = (f16_t)rS[i].x; h4[1] = (f16_t)rS[i].y;
            h4[2] = (f16_t)rS[i].z; h4[3] = (f16_t)rS[i].w;
            *(f16x4*)&buf[eo] = h4;
        }
    };
    auto readF = [&](const f16_t* buf) {
#pragma unroll
        for (int i = 0; i < 4; ++i) aH[i] = *(const f16x8*)&buf[aro[i]];
#pragma unroll
        for (int j = 0; j < 4; ++j) bH[j] = *(const f16x8*)&buf[4096 + bro[j]];
    };

    loadR(0);
    stageG(lds[0], 0);
    writeR(lds[0]);
    loadR(32);
    asm volatile("s_waitcnt vmcnt(4)" ::: "memory");
    asm volatile("s_waitcnt lgkmcnt(0)" ::: "memory");
    __builtin_amdgcn_s_barrier();
    readF(lds[0]);
    asm volatile("s_waitcnt lgkmcnt(0)" ::: "memory");
    __builtin_amdgcn_s_barrier();

    for (int t = 0; t < NT; ++t) {
        f16_t* nxt = lds[(t & 1) ^ 1];
        const bool pf = (t + 1 < NT);

        if (pf) {
            writeR(nxt);
            stageG(nxt, (t + 1) << 5);
            if (t + 2 < NT) loadR((t + 2) << 5);
        }
#pragma unroll
        for (int j = 0; j < 4; ++j)
#pragma unroll
            for (int i = 0; i < 4; ++i)
                acc[i][j] = MFMA16H(aH[i], bH[j], acc[i][j]);

        if (pf && (t + 2 < NT))
            asm volatile("s_waitcnt vmcnt(4)" ::: "memory");
        else
            asm volatile("s_waitcnt vmcnt(0)" ::: "memory");
        asm volatile("s_waitcnt lgkmcnt(0)" ::: "memory");
        __builtin_amdgcn_s_barrier();
        if (pf) {
            readF(nxt);
            asm volatile("s_waitcnt lgkmcnt(0)" ::: "memory");
        }
        __builtin_amdgcn_s_barrier();
    }

    const int frow = q * 4;
#pragma unroll
    for (int i = 0; i < 4; ++i) {
        const int rgl = row0 + wr + i * 16 + frow;
#pragma unroll
        for (int j = 0; j < 4; ++j) {
            const int cg = col0 + wc + j * 16 + fr;
            float* Cp = C + bz * sC;
            const float badd = bias[cg];
#pragma unroll
            for (int r = 0; r < 4; ++r)
                Cp[(long)(rgl + r) * N + cg] = acc[i][j][r] + badd;
        }
    }
}

// ---------------------------------------------------------------------------
// Fallback pieces (fp32 path, used only if ws is too small)
__global__ __launch_bounds__(256)
void softmax_rows(float* __restrict__ S)
{
    const long row = (long)blockIdx.x * 4 + (threadIdx.x >> 6);
    const int lane = threadIdx.x & 63;
    float* p = S + row * (long)TENC;
    float4 v[4];
    float m = -INFINITY;
#pragma unroll
    for (int i = 0; i < 4; ++i) {
        v[i] = *(const float4*)&p[i * 256 + lane * 4];
        m = fmaxf(fmaxf(fmaxf(v[i].x, v[i].y), fmaxf(v[i].z, v[i].w)), m);
    }
#pragma unroll
    for (int o = 32; o; o >>= 1) m = fmaxf(m, __shfl_xor(m, o, 64));
    float s = 0.f;
#pragma unroll
    for (int i = 0; i < 4; ++i) {
        v[i].x = __expf(v[i].x - m); v[i].y = __expf(v[i].y - m);
        v[i].z = __expf(v[i].z - m); v[i].w = __expf(v[i].w - m);
        s += v[i].x + v[i].y + v[i].z + v[i].w;
    }
#pragma unroll
    for (int o = 32; o; o >>= 1) s += __shfl_xor(s, o, 64);
    const float inv = 1.0f / s;
#pragma unroll
    for (int i = 0; i < 4; ++i) {
        v[i].x *= inv; v[i].y *= inv; v[i].z *= inv; v[i].w *= inv;
        *(float4*)&p[i * 256 + lane * 4] = v[i];
    }
}

#define TILE_M 64
#define TILE_N 64
#define TILE_K 16
template<bool B_TRANS, bool ADD_BIAS>
__global__ __launch_bounds__(256)
void gemm_f32(const float* __restrict__ A, const float* __restrict__ Bm,
              const float* __restrict__ bias, float* __restrict__ C,
              int M, int N, int K, int lda, int ldb,
              long strideA, long strideB, long strideC)
{
    __shared__ float As[TILE_K][TILE_M + 4];
    __shared__ float Bs[TILE_K][TILE_N + 4];
    const int b = blockIdx.z;
    A += (long)b * strideA; Bm += (long)b * strideB; C += (long)b * strideC;
    const int tid = threadIdx.x;
    const int tx = tid & 15, ty = tid >> 4;
    const int row0 = blockIdx.y * TILE_M, col0 = blockIdx.x * TILE_N;
    const int am = tid >> 2, ak = (tid & 3) * 4;
    float acc[4][4] = {};
    for (int kt = 0; kt < K; kt += TILE_K) {
        float4 a4 = *(const float4*)&A[(long)(row0 + am) * lda + kt + ak];
        float4 b4;
        if (B_TRANS) b4 = *(const float4*)&Bm[(long)(col0 + am) * ldb + kt + ak];
        else {
            const int bk_ = tid >> 4, bn = (tid & 15) * 4;
            b4 = *(const float4*)&Bm[(long)(kt + bk_) * ldb + col0 + bn];
        }
        __syncthreads();
        As[ak + 0][am] = a4.x; As[ak + 1][am] = a4.y;
        As[ak + 2][am] = a4.z; As[ak + 3][am] = a4.w;
        if (B_TRANS) {
            Bs[ak + 0][am] = b4.x; Bs[ak + 1][am] = b4.y;
            Bs[ak + 2][am] = b4.z; Bs[ak + 3][am] = b4.w;
        } else {
            const int bk_ = tid >> 4, bn = (tid & 15) * 4;
            *(float4*)&Bs[bk_][bn] = b4;
        }
        __syncthreads();
#pragma unroll
        for (int k = 0; k < TILE_K; ++k) {
            float4 av = *(const float4*)&As[k][ty * 4];
            float4 bv4 = *(const float4*)&Bs[k][tx * 4];
            float ar[4] = {av.x, av.y, av.z, av.w};
            float br[4] = {bv4.x, bv4.y, bv4.z, bv4.w};
#pragma unroll
            for (int i = 0; i < 4; ++i)
#pragma unroll
                for (int j = 0; j < 4; ++j)
                    acc[i][j] = fmaf(ar[i], br[j], acc[i][j]);
        }
    }
    float4 bias4 = make_float4(0.f, 0.f, 0.f, 0.f);
    if (ADD_BIAS) bias4 = *(const float4*)&bias[col0 + tx * 4];
#pragma unroll
    for (int i = 0; i < 4; ++i) {
        float4 o;
        o.x = acc[i][0] + bias4.x; o.y = acc[i][1] + bias4.y;
        o.z = acc[i][2] + bias4.z; o.w = acc[i][3] + bias4.w;
        *(float4*)&C[(long)(row0 + ty * 4 + i) * N + col0 + tx * 4] = o;
    }
}

// ---------------------------------------------------------------------------
extern "C" void kernel_launch(void* const* d_in, const int* in_sizes, int n_in,
                              void* d_out, int out_size, void* d_ws, size_t ws_size,
                              hipStream_t stream)
{
    const float* enc = (const float*)d_in[0];   // [32,1024,512]
    const float* dec = (const float*)d_in[1];   // [32,512,512]
    const float* Wk  = (const float*)d_in[2];   // [512,512]
    const float* Wv  = (const float*)d_in[4];   // [512,512]
    const float* bv  = (const float*)d_in[5];   // [512]

    const long nD = (long)BB * TDEC * NST;      // 8388608

    float* ctx   = (float*)d_out;               // [32,512,512]
    float* attnF = ctx + nD;                    // [32,512,1024]

    const size_t need = 68157440;
    const dim3 blk(256);

    if (ws_size < need) {
        float* ws = (float*)d_ws;
        gemm_f32<true, false><<<dim3(DDIM / 64, (BB * TDEC) / 64, 1), blk, 0, stream>>>(
            dec, Wk, nullptr, ws, BB * TDEC, DDIM, NST, NST, NST, 0, 0, 0);
        gemm_f32<true, false><<<dim3(TENC / 64, TDEC / 64, BB), blk, 0, stream>>>(
            ws, enc, nullptr, attnF, TDEC, TENC, DDIM, DDIM, DDIM,
            (long)TDEC * DDIM, (long)TENC * DDIM, (long)TDEC * TENC);
        softmax_rows<<<(BB * TDEC) / 4, blk, 0, stream>>>(attnF);
        gemm_f32<false, false><<<dim3(DDIM / 64, TDEC / 64, BB), blk, 0, stream>>>(
            attnF, enc, nullptr, ws, TDEC, DDIM, TENC, TENC, DDIM,
            (long)TDEC * TENC, (long)TENC * DDIM, (long)TDEC * DDIM);
        gemm_f32<false, true><<<dim3(NST / 64, (BB * TDEC) / 64, 1), blk, 0, stream>>>(
            ws, Wv, bv, ctx, BB * TDEC, NST, DDIM, DDIM, NST, 0, 0, 0);
        return;
    }

    // ws: EVT 33.55MB | Ef16 33.55MB | Wk16 0.5MB | WvT16 0.5MB
    char* w = (char*)d_ws;
    f16_t* EVT   = (f16_t*)(w);
    f16_t* Ef16  = (f16_t*)(w + 33554432);
    f16_t* Wk16  = (f16_t*)(w + 67108864);
    f16_t* WvT16 = (f16_t*)(w + 67633152);

    // dec16/DK16 in the not-yet-written ctx output region (16.8MB each)
    f16_t* dec16 = (f16_t*)ctx;
    f16_t* DK16  = dec16 + nD;

    // 1) fused prep (enc/dec/Wk cvt + Wv transpose)
    prep_convert<<<12480, blk, 0, stream>>>(enc, dec, Wk, Wv,
                                            Ef16, dec16, Wk16, WvT16);

    // 2) DK = dec @ Wk^T -> f16
    gemm_h<2><<<dim3(DDIM / 128, (BB * TDEC) / 128, 1), blk, 0, stream>>>(
        dec16, Wk16, nullptr, DK16,
        BB * TDEC, DDIM, NST, 0, 0, 0);

    // 3) EVT[v,te] = sum_d Wv[d,v] enc[te,d] -> f16
    gemm_h<2><<<dim3(TENC / 128, NST / 128, BB), blk, 0, stream>>>(
        WvT16, Ef16, nullptr, EVT,
        NST, TENC, DDIM,
        0, (long)TENC * DDIM, (long)NST * TENC);

    // 4) fused score + softmax (double-buffered) -> attn f32 directly
    score_softmax<<<dim3(16, 32), dim3(512), 0, stream>>>(DK16, Ef16, attnF);

    // 5) ctx = attn @ EV + bv  (A = attn f32 reg-staged, B = EVT gload)
    gemm_ctx<<<dim3(NST / 128, TDEC / 128, BB), blk, 0, stream>>>(
        attnF, EVT, bv, ctx,
        TDEC, NST, TENC,
        (long)TDEC * TENC, (long)NST * TENC, (long)TDEC * NST);
}